// Round 5
// baseline (3168.633 us; speedup 1.0000x reference)
//
#include <hip/hip_runtime.h>
#include <stdint.h>

typedef __bf16 bf16;
typedef __attribute__((ext_vector_type(8))) __bf16 bf16x8;
typedef __attribute__((ext_vector_type(4))) float f32x4;

#define GRU_H 2048
#define ODIM 96
#define PADX 128
#define BATCH 1024
#define TSTEPS 25

__device__ __forceinline__ float sigm(float x) { return 1.f / (1.f + __expf(-x)); }

__device__ __forceinline__ void gload16(const void* g, void* l) {
  __builtin_amdgcn_global_load_lds((const __attribute__((address_space(1))) uint32_t*)g,
                                   (__attribute__((address_space(3))) uint32_t*)l, 16, 0, 0);
}

// ---------------- init / convert kernels ----------------
__global__ void k_cvt(const float* __restrict__ s, bf16* __restrict__ d, int n) {
  int stride = gridDim.x * blockDim.x;
  for (int i = blockIdx.x * blockDim.x + threadIdx.x; i < n; i += stride)
    d[i] = (bf16)s[i];
}

__global__ void k_cvt_pad(const float* __restrict__ s, bf16* __restrict__ d,
                          int rows, int cin, int cout) {
  int n = rows * cout;
  int stride = gridDim.x * blockDim.x;
  for (int i = blockIdx.x * blockDim.x + threadIdx.x; i < n; i += stride) {
    int r = i / cout, c = i - r * cout;
    d[i] = (c < cin) ? (bf16)s[r * cin + c] : (bf16)0.f;
  }
}

__global__ void k_init_h(const float* __restrict__ s, float* __restrict__ hf,
                         bf16* __restrict__ hb, int n) {
  int stride = gridDim.x * blockDim.x;
  for (int i = blockIdx.x * blockDim.x + threadIdx.x; i < n; i += stride) {
    float v = s[i];
    hf[i] = v;
    hb[i] = (bf16)v;
  }
}

// ---------------- fused GRU layer kernel ----------------
// 256 thr = 4 waves: wm = w&1 (row half of 64), wn = w>>1 (32-H-col half).
// Block tile: 128 batch-rows x 64 H-cols x 3 gates. Per wave: 64 rows x 32 cols
// x 3 gates = (mf=4) x (nf=6) frags -> 10 LDS reads per 24 MFMA per kf
// (vs 7/12 with 8 waves): per-CU LDS reads/step 112 -> 80, balancing the LDS
// pipe (~960 cyc) against the MFMA pipe (~931 cyc).
// grid (32, 8) = 256 blocks = 1 block/CU, 1 wave/SIMD. 3 LDS buffers, depth-2
// prefetch, ONE fused s_waitcnt vmcnt(10) lgkmcnt(0) + s_barrier per K-step.
__global__ __launch_bounds__(256, 1) void k_gru(
    const bf16* __restrict__ xb, int kx,          // x input [1024][kx], kx = 128 or 2048
    const bf16* __restrict__ hb,                  // h_prev bf16 [1024][2048]
    const bf16* __restrict__ wih,                 // [3*2048][kx]
    const bf16* __restrict__ whh,                 // [3*2048][2048]
    const float* __restrict__ bih, const float* __restrict__ bhh,
    const float* __restrict__ hprevf,             // h_prev fp32 master
    float* __restrict__ hnewf, bf16* __restrict__ hnewb) {
  __shared__ alignas(16) char sm[3][40960];       // per buffer: A 16KB (128x64) + B 24KB (192x64)

  const int tid = threadIdx.x;
  const int l = tid & 63;
  const int w = tid >> 6;
  const int wm = w & 1, wn = w >> 1;
  const int wb = tid & ~63;
  const int bn0 = blockIdx.x * 64;
  const int bm0 = blockIdx.y * 128;
  const int lm = l >> 4, ln = l & 15;
  char* sm0 = &sm[0][0];

  const int S1 = GRU_H / 64;                      // 32 hh steps
  const int S2 = kx / 64;                         // 2 or 32 ih steps
  const int S = S1 + S2;                          // 34 or 64; (S-1) % 3 == 0

  f32x4 accR[4][2] = {};
  f32x4 accZ[4][2] = {};
  f32x4 accNH[4][2] = {};
  f32x4 accNI[4][2] = {};

  // staging invariants: chunk c = it*256 + tid; row = c>>3 = row0 + it*32;
  // slot = (c&7) ^ (row&7) is it-invariant (rows step by 32).
  const int row0 = tid >> 3;                      // 0..31
  const int slot = (tid & 7) ^ (row0 & 7);
  const char* hbB  = (const char*)hb;
  const char* xbB  = (const char*)xb;
  const char* whhB = (const char*)whh;
  const char* wihB = (const char*)wih;
  const size_t colb = (size_t)slot * 16;
  const size_t aHH = (size_t)(bm0 + row0) * (GRU_H * 2) + colb;
  const size_t aIH = (size_t)(bm0 + row0) * ((size_t)kx * 2) + colb;
  const size_t bHH = (size_t)(bn0 + row0) * (GRU_H * 2) + colb;
  const size_t bIH = (size_t)(bn0 + row0) * ((size_t)kx * 2) + colb;

  auto stageHH = [&](int k0, char* sb) {
    size_t kb = (size_t)k0 * 2;
#pragma unroll
    for (int i = 0; i < 4; ++i)                   // A: rows step 32 -> +32*K bytes
      gload16(hbB + aHH + (size_t)i * (32 * GRU_H * 2) + kb,
              sb + ((i * 256 + wb) << 4));
#pragma unroll
    for (int i = 0; i < 6; ++i)                   // B: g = i>>1, r += (i&1)*32
      gload16(whhB + bHH + (size_t)(i >> 1) * ((size_t)GRU_H * GRU_H * 2)
                         + (size_t)(i & 1) * (32 * GRU_H * 2) + kb,
              sb + 16384 + ((i * 256 + wb) << 4));
  };
  auto stageIH = [&](int k0, char* sb) {
    size_t kb = (size_t)k0 * 2;
#pragma unroll
    for (int i = 0; i < 4; ++i)
      gload16(xbB + aIH + (size_t)i * ((size_t)32 * kx * 2) + kb,
              sb + ((i * 256 + wb) << 4));
#pragma unroll
    for (int i = 0; i < 6; ++i)
      gload16(wihB + bIH + (size_t)(i >> 1) * ((size_t)GRU_H * kx * 2)
                         + (size_t)(i & 1) * ((size_t)32 * kx * 2) + kb,
              sb + 16384 + ((i * 256 + wb) << 4));
  };

  auto computeStep = [&](const char* bp, f32x4 (&accN)[4][2]) {
#pragma unroll
    for (int kf = 0; kf < 2; ++kf) {
      const int pos = ((kf * 4 + lm) ^ (ln & 7)) << 4;
      bf16x8 af[4];
#pragma unroll
      for (int mf = 0; mf < 4; ++mf)
        af[mf] = *(const bf16x8*)(bp + (wm * 64 + mf * 16 + ln) * 128 + pos);
#pragma unroll
      for (int g = 0; g < 3; ++g) {
        bf16x8 bq[2];
#pragma unroll
        for (int jf = 0; jf < 2; ++jf)
          bq[jf] = *(const bf16x8*)(bp + 16384 + (g * 64 + wn * 32 + jf * 16 + ln) * 128 + pos);
        f32x4 (*acc)[2] = (g == 0) ? accR : (g == 1) ? accZ : accN;
#pragma unroll
        for (int mf = 0; mf < 4; ++mf)
#pragma unroll
          for (int jf = 0; jf < 2; ++jf)
            acc[mf][jf] = __builtin_amdgcn_mfma_f32_16x16x32_bf16(af[mf], bq[jf], acc[mf][jf], 0, 0, 0);
      }
    }
  };

  auto body = [&](int s, char* bufR, char* bufW) {
    // vmcnt(10): stage(s+1)'s 10 loads may stay in flight; stage(s) is drained.
    // lgkmcnt(0): my ds_reads of the buffer bufW replaces are complete (WAR-safe).
    asm volatile("s_waitcnt vmcnt(10) lgkmcnt(0)\ns_barrier" ::: "memory");
    if (s + 2 < S) {
      if (s + 2 < S1) stageHH((s + 2) * 64, bufW);
      else            stageIH((s + 2 - S1) * 64, bufW);
    }
    __builtin_amdgcn_s_setprio(1);
    if (s < S1) computeStep(bufR, accNH);
    else        computeStep(bufR, accNI);
    __builtin_amdgcn_s_setprio(0);
  };

  // prologue: fill 2 deep (steps 0,1 are always hh since S1 >= 2)
  stageHH(0, sm0);
  stageHH(64, sm0 + 40960);

  const int SM1 = S - 1;                          // 33 or 63, divisible by 3
  for (int s = 0; s < SM1; s += 3) {
    body(s + 0, sm0,         sm0 + 81920);
    body(s + 1, sm0 + 40960, sm0);
    body(s + 2, sm0 + 81920, sm0 + 40960);
  }
  // tail step SM1 (always in ih phase): buffer SM1 % 3 == 0
  asm volatile("s_waitcnt vmcnt(0) lgkmcnt(0)\ns_barrier" ::: "memory");
  __builtin_amdgcn_s_setprio(1);
  computeStep(sm0, accNI);
  __builtin_amdgcn_s_setprio(0);

  // ---- GRU epilogue ----
#pragma unroll
  for (int jf = 0; jf < 2; ++jf) {
    int j = bn0 + wn * 32 + jf * 16 + ln;
    float br = bih[j] + bhh[j];
    float bz = bih[GRU_H + j] + bhh[GRU_H + j];
    float bin = bih[2 * GRU_H + j];
    float bhn = bhh[2 * GRU_H + j];
#pragma unroll
    for (int mf = 0; mf < 4; ++mf) {
#pragma unroll
      for (int rr = 0; rr < 4; ++rr) {
        int m = bm0 + wm * 64 + mf * 16 + lm * 4 + rr;
        size_t idx = (size_t)m * GRU_H + j;
        float hp = hprevf[idx];
        float rg = sigm(accR[mf][jf][rr] + br);
        float zg = sigm(accZ[mf][jf][rr] + bz);
        float ng = tanhf(accNI[mf][jf][rr] + bin + rg * (accNH[mf][jf][rr] + bhn));
        float hn = (1.f - zg) * ng + zg * hp;
        hnewf[idx] = hn;
        hnewb[idx] = (bf16)hn;
      }
    }
  }
}

// ---------------- FC (split-K) ----------------
// grid.x = 16 K-chunks of 128, grid.y = 16 M-tiles of 64. 256 thr = 4 waves.
__global__ __launch_bounds__(256, 1) void k_fc_part(const bf16* __restrict__ h1b,
                                                    const bf16* __restrict__ wfc,
                                                    float* __restrict__ part) {
  const int kc = blockIdx.x;
  const int mt = blockIdx.y;
  const int l = threadIdx.x & 63, w = threadIdx.x >> 6;
  const int lm = l >> 4, ln = l & 15;
  const int m0 = mt * 64 + w * 16;
  const int k0 = kc * 128;
  f32x4 acc[6] = {};
#pragma unroll
  for (int kf = 0; kf < 4; ++kf) {
    bf16x8 a = *(const bf16x8*)&h1b[(size_t)(m0 + ln) * GRU_H + k0 + kf * 32 + lm * 8];
#pragma unroll
    for (int nf = 0; nf < 6; ++nf) {
      bf16x8 b = *(const bf16x8*)&wfc[(size_t)(nf * 16 + ln) * GRU_H + k0 + kf * 32 + lm * 8];
      acc[nf] = __builtin_amdgcn_mfma_f32_16x16x32_bf16(a, b, acc[nf], 0, 0, 0);
    }
  }
  float* base = part + (size_t)kc * (BATCH * ODIM);
#pragma unroll
  for (int nf = 0; nf < 6; ++nf)
#pragma unroll
    for (int rr = 0; rr < 4; ++rr)
      base[(size_t)(m0 + lm * 4 + rr) * ODIM + nf * 16 + ln] = acc[nf][rr];
}

__global__ void k_fc_red(const float* __restrict__ part, const float* __restrict__ bfc,
                         float* __restrict__ dout, bf16* __restrict__ decb, int t) {
  int i = blockIdx.x * blockDim.x + threadIdx.x;
  if (i >= BATCH * ODIM) return;
  int m = i / ODIM, n = i - m * ODIM;
  float s = bfc[n];
#pragma unroll
  for (int kc = 0; kc < 16; ++kc) s += part[(size_t)kc * (BATCH * ODIM) + i];
  s = sigm(s);
  dout[(size_t)m * (TSTEPS * ODIM) + t * ODIM + n] = s;
  decb[m * PADX + n] = (bf16)s;
}

// ---------------- launch ----------------
extern "C" void kernel_launch(void* const* d_in, const int* in_sizes, int n_in,
                              void* d_out, int out_size, void* d_ws, size_t ws_size,
                              hipStream_t stream) {
  const float* input   = (const float*)d_in[0];
  const float* hiddens = (const float*)d_in[2];
  const float* W_ih0   = (const float*)d_in[3];
  const float* W_hh0   = (const float*)d_in[4];
  const float* b_ih0   = (const float*)d_in[5];
  const float* b_hh0   = (const float*)d_in[6];
  const float* W_ih1   = (const float*)d_in[7];
  const float* W_hh1   = (const float*)d_in[8];
  const float* b_ih1   = (const float*)d_in[9];
  const float* b_hh1   = (const float*)d_in[10];
  const float* W_fc    = (const float*)d_in[11];
  const float* b_fc    = (const float*)d_in[12];
  float* out = (float*)d_out;

  char* p = (char*)d_ws;
  auto take = [&](size_t n) { char* q = p; p += (n + 255) & ~(size_t)255; return q; };
  bf16* wih0b = (bf16*)take((size_t)3 * GRU_H * PADX * 2);
  bf16* whh0b = (bf16*)take((size_t)3 * GRU_H * GRU_H * 2);
  bf16* wih1b = (bf16*)take((size_t)3 * GRU_H * GRU_H * 2);
  bf16* whh1b = (bf16*)take((size_t)3 * GRU_H * GRU_H * 2);
  bf16* wfcb  = (bf16*)take((size_t)ODIM * GRU_H * 2);
  bf16* decb  = (bf16*)take((size_t)BATCH * PADX * 2);
  float* h0f[2], *h1f[2];
  bf16* h0b[2], *h1b[2];
  h0f[0] = (float*)take((size_t)BATCH * GRU_H * 4);
  h0f[1] = (float*)take((size_t)BATCH * GRU_H * 4);
  h1f[0] = (float*)take((size_t)BATCH * GRU_H * 4);
  h1f[1] = (float*)take((size_t)BATCH * GRU_H * 4);
  h0b[0] = (bf16*)take((size_t)BATCH * GRU_H * 2);
  h0b[1] = (bf16*)take((size_t)BATCH * GRU_H * 2);
  h1b[0] = (bf16*)take((size_t)BATCH * GRU_H * 2);
  h1b[1] = (bf16*)take((size_t)BATCH * GRU_H * 2);
  float* fcpart = (float*)take((size_t)16 * BATCH * ODIM * 4);

  // one-time (per launch) conversions
  k_cvt_pad<<<768, 256, 0, stream>>>(W_ih0, wih0b, 3 * GRU_H, ODIM, PADX);
  k_cvt<<<2048, 256, 0, stream>>>(W_hh0, whh0b, 3 * GRU_H * GRU_H);
  k_cvt<<<2048, 256, 0, stream>>>(W_ih1, wih1b, 3 * GRU_H * GRU_H);
  k_cvt<<<2048, 256, 0, stream>>>(W_hh1, whh1b, 3 * GRU_H * GRU_H);
  k_cvt<<<192, 256, 0, stream>>>(W_fc, wfcb, ODIM * GRU_H);
  k_cvt_pad<<<512, 256, 0, stream>>>(input, decb, BATCH, ODIM, PADX);
  k_init_h<<<2048, 256, 0, stream>>>(hiddens, h0f[0], h0b[0], BATCH * GRU_H);
  k_init_h<<<2048, 256, 0, stream>>>(hiddens + (size_t)BATCH * GRU_H, h1f[0], h1b[0], BATCH * GRU_H);

  int cur = 0;
  for (int t = 0; t < TSTEPS; ++t) {
    int nxt = cur ^ 1;
    k_gru<<<dim3(32, 8), 256, 0, stream>>>(decb, PADX, h0b[cur], wih0b, whh0b,
                                           b_ih0, b_hh0, h0f[cur], h0f[nxt], h0b[nxt]);
    k_gru<<<dim3(32, 8), 256, 0, stream>>>(h0b[nxt], GRU_H, h1b[cur], wih1b, whh1b,
                                           b_ih1, b_hh1, h1f[cur], h1f[nxt], h1b[nxt]);
    k_fc_part<<<dim3(16, 16), 256, 0, stream>>>(h1b[nxt], wfcb, fcpart);
    k_fc_red<<<384, 256, 0, stream>>>(fcpart, b_fc, out, decb, t);
    cur = nxt;
  }
}